// Round 4
// baseline (661.387 us; speedup 1.0000x reference)
//
#include <hip/hip_runtime.h>
#include <hip/hip_cooperative_groups.h>
#include <math.h>

namespace cg = cooperative_groups;

#define NQ 32768      // queue rows of A = Q^T [N, C]
#define NC 1000       // clusters
#define NC4 250       // float4s per row
#define CHUNK 8       // rows per wave per grid-stride step
#define MAXBLK 1024   // 1024 blocks * 4 waves * 8 rows = 32768 rows

__device__ __forceinline__ float wredsum(float v) {
#pragma unroll
    for (int off = 32; off > 0; off >>= 1) v += __shfl_xor(v, off, 64);
    return v;
}

// Stream all owned rows of A; fn(row, e[4]) gets E = exp(2*a) as float4[4]
// (lane-mapped c4 = k*64+lane; inactive lanes see e=1 but are masked by sf=0
// or guarded stores). One-row prefetch inside each 8-row chunk.
template <typename F>
__device__ __forceinline__ void stream_all(const float* __restrict__ A, int gw,
                                           int nwaves, int lane, F&& fn) {
    for (int r0 = gw * CHUNK; r0 < NQ; r0 += nwaves * CHUNK) {
        float4 nxt[4];
        const float4* rp0 = reinterpret_cast<const float4*>(A + (size_t)r0 * NC);
#pragma unroll
        for (int k = 0; k < 4; ++k) {
            const int c4 = k * 64 + lane;
            nxt[k] = (c4 < NC4) ? rp0[c4] : make_float4(0.f, 0.f, 0.f, 0.f);
        }
        for (int r = 0; r < CHUNK; ++r) {
            float4 cur[4];
#pragma unroll
            for (int k = 0; k < 4; ++k) cur[k] = nxt[k];
            if (r + 1 < CHUNK) {  // prefetch next row before the exp/compute
                const float4* rp =
                    reinterpret_cast<const float4*>(A + (size_t)(r0 + r + 1) * NC);
#pragma unroll
                for (int k = 0; k < 4; ++k) {
                    const int c4 = k * 64 + lane;
                    if (c4 < NC4) nxt[k] = rp[c4];
                }
            }
            float4 e[4];
#pragma unroll
            for (int k = 0; k < 4; ++k) {
                e[k].x = __expf(2.f * cur[k].x);
                e[k].y = __expf(2.f * cur[k].y);
                e[k].z = __expf(2.f * cur[k].z);
                e[k].w = __expf(2.f * cur[k].w);
            }
            fn(r0 + r, e);
        }
    }
}

// Single-kernel separable Sinkhorn:
//   G0 = colsum(E); rank -> Ksc; s1 = Ksc/G0
//   r_t[n] = 1/sum_c(E*s_t); G_t[c] = sum_n(E*r_t); s_{t+1} = Ksc/G_t
//   out = E * s3 * r3   (rows sum to 1; clip(1e-16) provably dead)
__global__ __launch_bounds__(256, 4) void k_sink(const float* __restrict__ A,
                                                 const float* __restrict__ lk,
                                                 float* __restrict__ out,
                                                 float* __restrict__ G) {
    cg::grid_group grid = cg::this_grid();
    __shared__ __align__(16) float sacc[1024];  // col partials / G0 scratch
    __shared__ __align__(16) float sKsc[1024];  // K[rank(c)]
    __shared__ __align__(16) float sSv[1024];   // current s vector
    __shared__ float sred[4];

    const int tid = threadIdx.x;
    const int lane = tid & 63;
    const int gw = (blockIdx.x * 256 + tid) >> 6;
    const int nwaves = (gridDim.x * 256) >> 6;

    float* G0 = G;
    float* G1 = G + 1024;
    float* G2 = G + 2048;

    // ---------------- P0: G0 = colsum(exp(2A)) ----------------
    for (int i = tid; i < 1024; i += 256) sacc[i] = 0.f;
    __syncthreads();
    {
        float acc[16];
#pragma unroll
        for (int i = 0; i < 16; ++i) acc[i] = 0.f;
        stream_all(A, gw, nwaves, lane, [&](int, const float4* e) {
#pragma unroll
            for (int k = 0; k < 4; ++k) {
                acc[4 * k + 0] += e[k].x; acc[4 * k + 1] += e[k].y;
                acc[4 * k + 2] += e[k].z; acc[4 * k + 3] += e[k].w;
            }
        });
#pragma unroll
        for (int k = 0; k < 4; ++k) {
            const int c4 = k * 64 + lane;
            if (c4 < NC4) {
                atomicAdd(&sacc[4 * c4 + 0], acc[4 * k + 0]);
                atomicAdd(&sacc[4 * c4 + 1], acc[4 * k + 1]);
                atomicAdd(&sacc[4 * c4 + 2], acc[4 * k + 2]);
                atomicAdd(&sacc[4 * c4 + 3], acc[4 * k + 3]);
            }
        }
        __syncthreads();
        for (int i = tid; i < NC; i += 256) atomicAdd(&G0[i], sacc[i]);
    }
    grid.sync();

    // -------- rank + Ksc + s1 (redundant per block, ~4us, fully parallel) ---
    for (int i = tid; i < 1024; i += 256) sacc[i] = (i < NC) ? G0[i] : 0.f;
    const float L = -log1pf(expf(-lk[0]));  // log(sigmoid(k)) <= 0
    float part = 0.f;
    for (int i = tid; i < NC; i += 256) part += expf((float)i * (1.f / 999.f) * L);
    part = wredsum(part);
    if (lane == 0) sred[tid >> 6] = part;
    __syncthreads();
    const float denom = sred[0] + sred[1] + sred[2] + sred[3];
    for (int c = tid; c < 1024; c += 256) {
        if (c < NC) {
            const float sc = sacc[c];
            int p = 0;
#pragma unroll 4
            for (int j = 0; j < NC; ++j) {
                const float sj = sacc[j];  // broadcast read, conflict-free
                p += (sj > sc) || (sj == sc && j < c);  // stable descending rank
            }
            const float ks = expf((float)p * (1.f / 999.f) * L) / denom;
            sKsc[c] = ks;
            sSv[c] = ks / sc;
        } else {
            sKsc[c] = 0.f;
            sSv[c] = 0.f;
        }
    }
    __syncthreads();

    const float4* S4 = reinterpret_cast<const float4*>(sSv);

    // ---------------- P1 / P2: accumulate G1 / G2 ----------------
#pragma unroll 1
    for (int it = 0; it < 2; ++it) {
        float* Gn = (it == 0) ? G1 : G2;
        float4 sf[4];
#pragma unroll
        for (int k = 0; k < 4; ++k) sf[k] = S4[k * 64 + lane];
        __syncthreads();  // all reads of sacc (rank) / sSv done
        for (int i = tid; i < 1024; i += 256) sacc[i] = 0.f;
        __syncthreads();
        float acc[16];
#pragma unroll
        for (int i = 0; i < 16; ++i) acc[i] = 0.f;
        stream_all(A, gw, nwaves, lane, [&](int, const float4* e) {
            float t = 0.f;
#pragma unroll
            for (int k = 0; k < 4; ++k)
                t += e[k].x * sf[k].x + e[k].y * sf[k].y +
                     e[k].z * sf[k].z + e[k].w * sf[k].w;
            t = wredsum(t);
            const float rr = 1.f / t;
#pragma unroll
            for (int k = 0; k < 4; ++k) {
                acc[4 * k + 0] += e[k].x * rr; acc[4 * k + 1] += e[k].y * rr;
                acc[4 * k + 2] += e[k].z * rr; acc[4 * k + 3] += e[k].w * rr;
            }
        });
#pragma unroll
        for (int k = 0; k < 4; ++k) {
            const int c4 = k * 64 + lane;
            if (c4 < NC4) {
                atomicAdd(&sacc[4 * c4 + 0], acc[4 * k + 0]);
                atomicAdd(&sacc[4 * c4 + 1], acc[4 * k + 1]);
                atomicAdd(&sacc[4 * c4 + 2], acc[4 * k + 2]);
                atomicAdd(&sacc[4 * c4 + 3], acc[4 * k + 3]);
            }
        }
        __syncthreads();
        for (int i = tid; i < NC; i += 256) atomicAdd(&Gn[i], sacc[i]);
        grid.sync();
        for (int i = tid; i < 1024; i += 256)
            sSv[i] = (i < NC) ? sKsc[i] / Gn[i] : 0.f;
        __syncthreads();
    }

    // ---------------- P3: out = E * s3 * r3 ----------------
    {
        float4 sf[4];
#pragma unroll
        for (int k = 0; k < 4; ++k) sf[k] = S4[k * 64 + lane];
        stream_all(A, gw, nwaves, lane, [&](int row, const float4* e) {
            float t = 0.f;
#pragma unroll
            for (int k = 0; k < 4; ++k)
                t += e[k].x * sf[k].x + e[k].y * sf[k].y +
                     e[k].z * sf[k].z + e[k].w * sf[k].w;
            t = wredsum(t);
            const float rr = 1.f / t;
            float4* op = reinterpret_cast<float4*>(out + (size_t)row * NC);
#pragma unroll
            for (int k = 0; k < 4; ++k) {
                const int c4 = k * 64 + lane;
                if (c4 < NC4)
                    op[c4] = make_float4(e[k].x * sf[k].x * rr,
                                         e[k].y * sf[k].y * rr,
                                         e[k].z * sf[k].z * rr,
                                         e[k].w * sf[k].w * rr);
            }
        });
    }
}

extern "C" void kernel_launch(void* const* d_in, const int* in_sizes, int n_in,
                              void* d_out, int out_size, void* d_ws, size_t ws_size,
                              hipStream_t stream) {
    const float* A = (const float*)d_in[0];
    const float* lk = (const float*)d_in[1];
    float* out = (float*)d_out;
    float* G = (float*)d_ws;

    hipMemsetAsync(G, 0, 3072 * sizeof(float), stream);  // zero G0,G1,G2

    // Size the cooperative grid from the occupancy query (capture-safe, pure query).
    int nblk = MAXBLK;
    int per_cu = 0;
    if (hipOccupancyMaxActiveBlocksPerMultiprocessor(&per_cu, k_sink, 256, 0) ==
            hipSuccess && per_cu > 0) {
        int dev = 0, ncu = 0;
        hipGetDevice(&dev);
        hipDeviceGetAttribute(&ncu, hipDeviceAttributeMultiprocessorCount, dev);
        if (ncu <= 0) ncu = 256;
        long cap = (long)per_cu * (long)ncu;
        if (cap < nblk) nblk = (int)cap;
    }
    if (nblk < 1) nblk = 1;

    void* args[] = {(void*)&A, (void*)&lk, (void*)&out, (void*)&G};
    hipLaunchCooperativeKernel(k_sink, dim3(nblk), dim3(256), args, 0, stream);
}

// Round 6
// 467.986 us; speedup vs baseline: 1.4133x; 1.4133x over previous
//
#include <hip/hip_runtime.h>
#include <math.h>
#include <type_traits>

#define NQ 32768     // queue rows of A = Q^T [N, C]
#define NC 1000      // clusters
#define NCH 250      // 4-element column chunks per row
#define PST 1024     // partial row stride (floats)

typedef unsigned int u32;
typedef unsigned short u16;

__device__ __forceinline__ float wredsum(float v) {
#pragma unroll
    for (int off = 32; off > 0; off >>= 1) v += __shfl_xor(v, off, 64);
    return v;
}

struct BufF { float4 v[4]; };
struct BufH { uint2 v[4]; };

__device__ __forceinline__ void loadRow(BufF& b, const float* __restrict__ A,
                                        int row, int lane) {
    const float4* rp = reinterpret_cast<const float4*>(A + (size_t)row * NC);
#pragma unroll
    for (int k = 0; k < 4; ++k) {
        const int c = k * 64 + lane;
        if (c < NCH) b.v[k] = rp[c];
        else b.v[k] = make_float4(0.f, 0.f, 0.f, 0.f);
    }
}
__device__ __forceinline__ void loadRow(BufH& b, const u16* __restrict__ E,
                                        int row, int lane) {
    const uint2* rp = reinterpret_cast<const uint2*>(E + (size_t)row * NC);
#pragma unroll
    for (int k = 0; k < 4; ++k) {
        const int c = k * 64 + lane;
        if (c < NCH) b.v[k] = rp[c];
        else b.v[k] = make_uint2(0u, 0u);
    }
}

__device__ __forceinline__ float bf2f(u32 bits) {
    union { u32 u; float f; } c; c.u = bits; return c.f;
}
// E = exp(2*a) for f32 source; plain convert for bf16 source.
__device__ __forceinline__ void conv(const BufF& b, float* e) {
#pragma unroll
    for (int k = 0; k < 4; ++k) {
        e[4 * k + 0] = __expf(2.f * b.v[k].x);
        e[4 * k + 1] = __expf(2.f * b.v[k].y);
        e[4 * k + 2] = __expf(2.f * b.v[k].z);
        e[4 * k + 3] = __expf(2.f * b.v[k].w);
    }
}
__device__ __forceinline__ void conv(const BufH& b, float* e) {
#pragma unroll
    for (int k = 0; k < 4; ++k) {
        e[4 * k + 0] = bf2f(b.v[k].x << 16);
        e[4 * k + 1] = bf2f(b.v[k].x & 0xffff0000u);
        e[4 * k + 2] = bf2f(b.v[k].y << 16);
        e[4 * k + 3] = bf2f(b.v[k].y & 0xffff0000u);
    }
}
__device__ __forceinline__ u32 f2bf_pair(float a, float bq) {
    union { float f; u32 u; } ca, cb; ca.f = a; cb.f = bq;
    const u32 ra = (ca.u + 0x7fffu + ((ca.u >> 16) & 1u)) >> 16;   // RNE
    const u32 rb = (cb.u + 0x7fffu + ((cb.u >> 16) & 1u)) & 0xffff0000u;
    return ra | rb;
}

// One streaming pass. SRC 0: f32 A (+exp); SRC 1: bf16 E.
// MODE 0: acc += E (WE: also store E as bf16)  -> per-block partials
// MODE 1: t = sum(E*s); r = 1/t; acc += E*r    -> per-block partials
// MODE 2: out = E*s*r                           -> final write, rows sum to 1
// One wave per row; 4-slot pipeline, 2 rows of loads in flight.
template <int SRC, int MODE, bool WE>
__global__ __launch_bounds__(256) void k_pass(
        const float* __restrict__ A, const u16* __restrict__ Ein,
        u16* __restrict__ Eout, const float* __restrict__ sv,
        float* __restrict__ outp, float* __restrict__ part) {
    __shared__ float sacc[PST];
    if (MODE < 2) {
        for (int i = threadIdx.x; i < PST; i += 256) sacc[i] = 0.f;
        __syncthreads();
    }
    const int lane = threadIdx.x & 63;
    const int w = (blockIdx.x * 256 + threadIdx.x) >> 6;
    const int nw = (gridDim.x * 256) >> 6;
    const int R = NQ / nw;  // rows per wave: 4 (G=2048) or 16 (G=512), %4==0

    float sf[16];
    if (MODE >= 1) {
        const float4* s4 = reinterpret_cast<const float4*>(sv);
#pragma unroll
        for (int k = 0; k < 4; ++k) {
            const int c = k * 64 + lane;
            const float4 t = (c < NCH) ? s4[c] : make_float4(0.f, 0.f, 0.f, 0.f);
            sf[4 * k + 0] = t.x; sf[4 * k + 1] = t.y;
            sf[4 * k + 2] = t.z; sf[4 * k + 3] = t.w;
        }
    }
    float acc[16];
    if (MODE < 2) {
#pragma unroll
        for (int i = 0; i < 16; ++i) acc[i] = 0.f;
    }

    using Buf = typename std::conditional<SRC == 0, BufF, BufH>::type;
    Buf b0, b1, b2, b3;
    int nld = 0;

    auto LD = [&](Buf& b) {
        if (nld < R) {
            if constexpr (SRC == 0) loadRow(b, A, w + nld * nw, lane);
            else                    loadRow(b, Ein, w + nld * nw, lane);
            ++nld;
        }
    };
    auto CMP = [&](Buf& b, int i) {
        const int row = w + i * nw;
        float e[16];
        conv(b, e);
        if constexpr (MODE == 0) {
#pragma unroll
            for (int j = 0; j < 16; ++j) acc[j] += e[j];
            if constexpr (WE) {
                uint2* ep = reinterpret_cast<uint2*>(Eout + (size_t)row * NC);
#pragma unroll
                for (int k = 0; k < 4; ++k) {
                    const int c = k * 64 + lane;
                    if (c < NCH)
                        ep[c] = make_uint2(f2bf_pair(e[4 * k + 0], e[4 * k + 1]),
                                           f2bf_pair(e[4 * k + 2], e[4 * k + 3]));
                }
            }
        } else {
            float t = 0.f;
#pragma unroll
            for (int j = 0; j < 16; ++j) t += e[j] * sf[j];
            t = wredsum(t);
            const float rr = 1.f / t;
            if constexpr (MODE == 1) {
#pragma unroll
                for (int j = 0; j < 16; ++j) acc[j] += e[j] * rr;
            } else {
                float4* op = reinterpret_cast<float4*>(outp + (size_t)row * NC);
#pragma unroll
                for (int k = 0; k < 4; ++k) {
                    const int c = k * 64 + lane;
                    if (c < NCH)
                        op[c] = make_float4(e[4 * k + 0] * sf[4 * k + 0] * rr,
                                            e[4 * k + 1] * sf[4 * k + 1] * rr,
                                            e[4 * k + 2] * sf[4 * k + 2] * rr,
                                            e[4 * k + 3] * sf[4 * k + 3] * rr);
                }
            }
        }
    };

    LD(b0); LD(b1);
    for (int q = 0; q < R; q += 4) {   // slot for row i = i%4; loads run 2 ahead
        LD(b2); CMP(b0, q + 0);
        LD(b3); CMP(b1, q + 1);
        LD(b0); CMP(b2, q + 2);
        LD(b1); CMP(b3, q + 3);
    }

    if (MODE < 2) {
#pragma unroll
        for (int k = 0; k < 4; ++k) {
            const int c = k * 64 + lane;
            if (c < NCH) {
                atomicAdd(&sacc[4 * c + 0], acc[4 * k + 0]);
                atomicAdd(&sacc[4 * c + 1], acc[4 * k + 1]);
                atomicAdd(&sacc[4 * c + 2], acc[4 * k + 2]);
                atomicAdd(&sacc[4 * c + 3], acc[4 * k + 3]);
            }
        }
        __syncthreads();
        float4* pp = reinterpret_cast<float4*>(part + (size_t)blockIdx.x * PST);
        const float4* sp = reinterpret_cast<const float4*>(sacc);
        pp[threadIdx.x] = sp[threadIdx.x];  // 256*16B = 4KB coalesced
    }
}

// partials[G][PST] -> mid[32][PST]; grid 128: pg=b>>2 (32), cg=b&3 (4x256 cols)
__global__ __launch_bounds__(256) void k_mid(const float* __restrict__ part,
                                             float* __restrict__ mid, int rpg) {
    const int pg = blockIdx.x >> 2;
    const int c = (blockIdx.x & 3) * 256 + threadIdx.x;
    float s = 0.f;
    const float* p0 = part + (size_t)pg * rpg * PST + c;
    for (int j = 0; j < rpg; ++j) s += p0[(size_t)j * PST];
    mid[pg * PST + c] = s;
}

// G0 = colsum(mid); stable descending rank; Ksc = K[rank]; sv = Ksc/G0.
// 8 blocks x 128 threads; block b ranks c in [125b, 125(b+1)).
__global__ __launch_bounds__(128) void k_rank(const float* __restrict__ mid,
                                              const float* __restrict__ lk,
                                              float* __restrict__ Ksc,
                                              float* __restrict__ sv) {
    __shared__ float sG[NC];
    __shared__ float sred[2];
    const int tid = threadIdx.x;
    for (int c = tid; c < NC; c += 128) {
        float s = 0.f;
#pragma unroll
        for (int m = 0; m < 32; ++m) s += mid[m * PST + c];
        sG[c] = s;
    }
    const float L = -log1pf(__expf(-lk[0]));  // log(sigmoid(k)) <= 0
    float pt = 0.f;
    for (int i = tid; i < NC; i += 128) pt += __expf((float)i * (1.f / 999.f) * L);
    pt = wredsum(pt);
    if ((tid & 63) == 0) sred[tid >> 6] = pt;
    __syncthreads();
    const float denom = sred[0] + sred[1];
    if (tid < 125) {
        const int c = blockIdx.x * 125 + tid;
        const float sc = sG[c];
        int p = 0;
#pragma unroll 4
        for (int j = 0; j < NC; ++j) {
            const float sj = sG[j];
            p += (sj > sc) || (sj == sc && j < c);  // stable descending rank
        }
        const float ks = __expf((float)p * (1.f / 999.f) * L) / denom;
        Ksc[c] = ks;
        sv[c] = ks / sc;
    }
}

// sv = Ksc / colsum(mid)
__global__ __launch_bounds__(128) void k_prepS(const float* __restrict__ mid,
                                               const float* __restrict__ Ksc,
                                               float* __restrict__ sv) {
    const int c = blockIdx.x * 128 + threadIdx.x;
    if (c < NC) {
        float s = 0.f;
#pragma unroll
        for (int m = 0; m < 32; ++m) s += mid[m * PST + c];
        sv[c] = Ksc[c] / s;
    }
}

extern "C" void kernel_launch(void* const* d_in, const int* in_sizes, int n_in,
                              void* d_out, int out_size, void* d_ws, size_t ws_size,
                              hipStream_t stream) {
    const float* A = (const float*)d_in[0];
    const float* lk = (const float*)d_in[1];
    float* out = (float*)d_out;
    float* ws = (float*)d_ws;
    float* Ksc = ws;                       // [1024]
    float* sv = ws + 1024;                 // [1024]
    float* mid = ws + 2048;                // [32][1024]
    float* part = ws + 2048 + 32 * 1024;   // [G][1024], G <= 2048
    u16* E = (u16*)(ws + 34816 + 2048 * 1024);  // bf16 E [NQ][NC] (tier 1)

    const size_t need_part2048 = (size_t)(34816 + 2048 * 1024) * 4u;
    const size_t need_E = need_part2048 + (size_t)NQ * NC * 2u;

    if (ws_size >= need_E) {
        // Tier 1: bf16 E cached; A read once.
        const int G = 2048;
        k_pass<0, 0, true><<<G, 256, 0, stream>>>(A, nullptr, E, nullptr, nullptr, part);
        k_mid<<<128, 256, 0, stream>>>(part, mid, G / 32);
        k_rank<<<8, 128, 0, stream>>>(mid, lk, Ksc, sv);
        k_pass<1, 1, false><<<G, 256, 0, stream>>>(nullptr, E, nullptr, sv, nullptr, part);
        k_mid<<<128, 256, 0, stream>>>(part, mid, G / 32);
        k_prepS<<<8, 128, 0, stream>>>(mid, Ksc, sv);
        k_pass<1, 1, false><<<G, 256, 0, stream>>>(nullptr, E, nullptr, sv, nullptr, part);
        k_mid<<<128, 256, 0, stream>>>(part, mid, G / 32);
        k_prepS<<<8, 128, 0, stream>>>(mid, Ksc, sv);
        k_pass<1, 2, false><<<G, 256, 0, stream>>>(nullptr, E, nullptr, sv, out, nullptr);
    } else {
        // Fallback: recompute exp from A every pass (f32 reads).
        const int G = (ws_size >= need_part2048) ? 2048 : 512;
        k_pass<0, 0, false><<<G, 256, 0, stream>>>(A, nullptr, nullptr, nullptr, nullptr, part);
        k_mid<<<128, 256, 0, stream>>>(part, mid, G / 32);
        k_rank<<<8, 128, 0, stream>>>(mid, lk, Ksc, sv);
        k_pass<0, 1, false><<<G, 256, 0, stream>>>(A, nullptr, nullptr, sv, nullptr, part);
        k_mid<<<128, 256, 0, stream>>>(part, mid, G / 32);
        k_prepS<<<8, 128, 0, stream>>>(mid, Ksc, sv);
        k_pass<0, 1, false><<<G, 256, 0, stream>>>(A, nullptr, nullptr, sv, nullptr, part);
        k_mid<<<128, 256, 0, stream>>>(part, mid, G / 32);
        k_prepS<<<8, 128, 0, stream>>>(mid, Ksc, sv);
        k_pass<0, 2, false><<<G, 256, 0, stream>>>(A, nullptr, nullptr, sv, out, nullptr);
    }
}